// Round 3
// baseline (73.666 us; speedup 1.0000x reference)
//
#include <hip/hip_runtime.h>

// MoE gate: logits = x @ W^T (x:[16384,2048] f32, W:[64,2048] f32),
// softmax over 64 experts, top-8 -> weights f32 + indices stored as f32.
//
// R3: two-kernel plan.
//  pack_w: W f32 -> MFMA-fragment-ordered bf16 3-way-split triples in d_ws
//          (768 KB, L2-resident, perfectly coalesced to load).
//  main:   grid 256 x 512thr, tile 64tok x 64exp, BK=64 double-buffered LDS.
//          x staged fragment-ordered via global_load_lds (pre-swizzled
//          per-lane source, linear LDS dest); W staged linearly. All ds_reads
//          lane-contiguous (conflict-free). 6-product bf16 MFMA ~= fp32.

typedef __attribute__((ext_vector_type(8))) short short8;
typedef __attribute__((ext_vector_type(4))) float f32x4;

#define NT    16384
#define DIMK  2048
#define NE    64
#define TOPKK 8
#define TT    64            // tokens per block (main)
#define CH    32            // K chunks of 64
#define WS_BYTES (CH * 24 * 1024)   // 786432

union U4S8 { unsigned int u[4]; short8 s; };

// Bit-exact 3-way bf16 split of 8 f32 (truncation split; subtractions exact).
__device__ __forceinline__ void split3(const float4 a, const float4 b,
                                       short8& H, short8& M, short8& L) {
    const float f[8] = {a.x, a.y, a.z, a.w, b.x, b.y, b.z, b.w};
    U4S8 uh, um, ul;
#pragma unroll
    for (int p = 0; p < 4; ++p) {
        const float f0 = f[2 * p], f1 = f[2 * p + 1];
        const unsigned int t0 = __float_as_uint(f0) & 0xFFFF0000u;
        const unsigned int t1 = __float_as_uint(f1) & 0xFFFF0000u;
        uh.u[p] = (t0 >> 16) | t1;
        const float r0 = f0 - __uint_as_float(t0);
        const float r1 = f1 - __uint_as_float(t1);
        const unsigned int v0 = __float_as_uint(r0) & 0xFFFF0000u;
        const unsigned int v1 = __float_as_uint(r1) & 0xFFFF0000u;
        um.u[p] = (v0 >> 16) | v1;
        const float s0 = r0 - __uint_as_float(v0);
        const float s1 = r1 - __uint_as_float(v1);
        ul.u[p] = (__float_as_uint(s0) >> 16) | (__float_as_uint(s1) & 0xFFFF0000u);
    }
    H = uh.s; M = um.s; L = ul.s;
}

__device__ __forceinline__ f32x4 mfma6(short8 ah, short8 am, short8 al,
                                       short8 bh, short8 bm, short8 bl, f32x4 c) {
    c = __builtin_amdgcn_mfma_f32_16x16x32_bf16(ah, bh, c, 0, 0, 0);
    c = __builtin_amdgcn_mfma_f32_16x16x32_bf16(ah, bm, c, 0, 0, 0);
    c = __builtin_amdgcn_mfma_f32_16x16x32_bf16(am, bh, c, 0, 0, 0);
    c = __builtin_amdgcn_mfma_f32_16x16x32_bf16(ah, bl, c, 0, 0, 0);
    c = __builtin_amdgcn_mfma_f32_16x16x32_bf16(am, bm, c, 0, 0, 0);
    c = __builtin_amdgcn_mfma_f32_16x16x32_bf16(al, bh, c, 0, 0, 0);
    return c;
}

__device__ __forceinline__ void async16(void* lds, const void* gp) {
    __builtin_amdgcn_global_load_lds(
        (const __attribute__((address_space(1))) unsigned int*)gp,
        (__attribute__((address_space(3))) unsigned int*)lds, 16, 0, 0);
}

// ---- pack W -> fragment-ordered bf16 triples in ws ----
// Layout: [c(32)][fw = (s'(2)*4 + n(4))*3 + t(3)][lane(64)][8 bf16]
// Fragment lane l: expert 16n + (l&15), k = 64c + 32s' + 8(l>>4) + 0..7.
__global__ __launch_bounds__(64) void pack_w_kernel(
    const float* __restrict__ W, short* __restrict__ wp)
{
    const int b = blockIdx.x;            // 0..255 = ((c*2)+s')*4 + n
    const int c = b >> 3, sp = (b >> 2) & 1, n = b & 3;
    const int l = threadIdx.x;
    const float* g = W + (size_t)(16 * n + (l & 15)) * DIMK
                       + 64 * c + 32 * sp + 8 * (l >> 4);
    const float4 lo = *(const float4*)g;
    const float4 hi = *(const float4*)(g + 4);
    short8 H, M, L;
    split3(lo, hi, H, M, L);
    const size_t base = ((size_t)c * 24 + (sp * 4 + n) * 3) * 512 + l * 8;
    *(short8*)(wp + base)        = H;
    *(short8*)(wp + base + 512)  = M;
    *(short8*)(wp + base + 1024) = L;
}

// ---- main fused kernel ----
__global__ __launch_bounds__(512, 1) void gate_main_kernel(
    const float* __restrict__ x, const short* __restrict__ wp,
    float* __restrict__ out)
{
    // x frags: fx = tg*4 + s'*2 + h (16 x 1KB); lane l: token 16tg+(l&15),
    //          k = 64c + 32s' + 8(l>>4) + 4h (4 floats).
    __shared__ __align__(16) float xs[2][4096];    // 2 x 16KB
    __shared__ __align__(16) short wl[2][12288];   // 2 x 24KB
    __shared__ float lg[TT][NE + 1];               // 16.6KB

    const int tid = threadIdx.x;
    const int w   = tid >> 6;           // 8 waves
    const int l   = tid & 63;
    const int tg  = w >> 1;             // token group 0..3 (16 tokens each)
    const int eg  = w & 1;              // expert group 0..1 (32 experts each)
    const int bt0 = blockIdx.x * TT;
    const int jj  = l & 15, gg = l >> 4;

    // per-wave stage sources (wave w stages x frags 2w,2w+1 and W frags 3w..3w+2)
    const int fx0 = 2 * w, fx1 = 2 * w + 1;
    const float* xg0 = x + (size_t)(bt0 + 16 * (fx0 >> 2) + jj) * DIMK
                         + 32 * ((fx0 >> 1) & 1) + 8 * gg + 4 * (fx0 & 1);
    const float* xg1 = x + (size_t)(bt0 + 16 * (fx1 >> 2) + jj) * DIMK
                         + 32 * ((fx1 >> 1) & 1) + 8 * gg + 4 * (fx1 & 1);
    const short* wg  = wp + ((size_t)3 * w) * 512 + l * 8;

    f32x4 acc[2];
#pragma unroll
    for (int n = 0; n < 2; ++n) acc[n] = (f32x4){0.f, 0.f, 0.f, 0.f};

    // prologue: stage chunk 0 into buf 0
    async16(&xs[0][fx0 * 256], xg0);
    async16(&xs[0][fx1 * 256], xg1);
#pragma unroll
    for (int i = 0; i < 3; ++i)
        async16(&wl[0][(3 * w + i) * 512], wg + (size_t)i * 512);
    __syncthreads();

#pragma unroll 2
    for (int c = 0; c < CH; ++c) {
        const int buf = c & 1;
        // stage c+1 into buf^1 (issue before compute; completes under it)
        if (c + 1 < CH) {
            async16(&xs[buf ^ 1][fx0 * 256], xg0 + 64 * (c + 1));
            async16(&xs[buf ^ 1][fx1 * 256], xg1 + 64 * (c + 1));
#pragma unroll
            for (int i = 0; i < 3; ++i)
                async16(&wl[buf ^ 1][(3 * w + i) * 512],
                        wg + ((size_t)(c + 1) * 24 + i) * 512);
        }

        // compute chunk c
#pragma unroll
        for (int sp = 0; sp < 2; ++sp) {
            const int fxa = tg * 4 + sp * 2;
            const float4 a0 = *(const float4*)&xs[buf][fxa * 256 + l * 4];
            const float4 a1 = *(const float4*)&xs[buf][(fxa + 1) * 256 + l * 4];
            short8 ah, am, al_;
            split3(a0, a1, ah, am, al_);
#pragma unroll
            for (int nt = 0; nt < 2; ++nt) {
                const int n = 2 * eg + nt;
                const int fb = (sp * 4 + n) * 3;
                const short8 bh = *(const short8*)&wl[buf][(fb + 0) * 512 + l * 8];
                const short8 bm = *(const short8*)&wl[buf][(fb + 1) * 512 + l * 8];
                const short8 bl = *(const short8*)&wl[buf][(fb + 2) * 512 + l * 8];
                acc[nt] = mfma6(ah, am, al_, bh, bm, bl, acc[nt]);
            }
        }
        __syncthreads();   // drains vmcnt (stage c+1 done) + all reads of buf
    }

    // ---- write logits; C/D: token = 16tg + 4*(l>>4) + q, expert = 32eg + 16nt + (l&15)
#pragma unroll
    for (int nt = 0; nt < 2; ++nt)
#pragma unroll
        for (int q = 0; q < 4; ++q)
            lg[16 * tg + 4 * gg + q][32 * eg + 16 * nt + jj] = acc[nt][q];
    __syncthreads();

    // ---- fused softmax + top-8: one lane per token ----
    if (tid < TT) {
        const float* rowp = &lg[tid][0];
        float mx = -3.402823466e38f;
        for (int e = 0; e < NE; ++e) mx = fmaxf(mx, rowp[e]);
        float sden = 0.f;
        for (int e = 0; e < NE; ++e) sden += expf(rowp[e] - mx);

        float tv[TOPKK];
        int   ti[TOPKK];
#pragma unroll
        for (int i = 0; i < TOPKK; ++i) { tv[i] = -3.402823466e38f; ti[i] = 0; }
        for (int e = 0; e < NE; ++e) {
            const float v = rowp[e];
            if (v > tv[TOPKK - 1]) {
                tv[TOPKK - 1] = v; ti[TOPKK - 1] = e;
#pragma unroll
                for (int q = TOPKK - 1; q > 0; --q) {
                    if (tv[q] > tv[q - 1]) {
                        const float fv = tv[q]; tv[q] = tv[q - 1]; tv[q - 1] = fv;
                        const int   iv = ti[q]; ti[q] = ti[q - 1]; ti[q - 1] = iv;
                    }
                }
            }
        }
        float* ow = out + (size_t)(bt0 + tid) * TOPKK;
        float* oi = out + (size_t)NT * TOPKK + (size_t)(bt0 + tid) * TOPKK;
#pragma unroll
        for (int i = 0; i < TOPKK; ++i) {
            ow[i] = expf(tv[i] - mx) / sden;
            oi[i] = (float)ti[i];
        }
    }
}

// ================= fallback (R2 kernel) if ws too small =================
__device__ __forceinline__ void load_step(const float* xp0, const float* xp1,
                                          const float* wp, int koff,
                                          float4 xb[2][2], float4 wb[4][2]) {
#pragma unroll
    for (int h = 0; h < 2; ++h) {
        xb[0][h] = *(const float4*)(xp0 + koff + 4 * h);
        xb[1][h] = *(const float4*)(xp1 + koff + 4 * h);
    }
#pragma unroll
    for (int n = 0; n < 4; ++n)
#pragma unroll
        for (int h = 0; h < 2; ++h)
            wb[n][h] = *(const float4*)(wp + (size_t)n * 16 * DIMK + koff + 4 * h);
}

__device__ __forceinline__ void do_step(const float4 xc[2][2], const float4 wc[4][2],
                                        f32x4 acc[2][4]) {
    short8 ah[2], am[2], al[2];
#pragma unroll
    for (int m = 0; m < 2; ++m) split3(xc[m][0], xc[m][1], ah[m], am[m], al[m]);
#pragma unroll
    for (int n = 0; n < 4; ++n) {
        short8 bh, bm, bl;
        split3(wc[n][0], wc[n][1], bh, bm, bl);
#pragma unroll
        for (int m = 0; m < 2; ++m)
            acc[m][n] = mfma6(ah[m], am[m], al[m], bh, bm, bl, acc[m][n]);
    }
}

__global__ __launch_bounds__(256, 2) void gate_fallback_kernel(
    const float* __restrict__ x, const float* __restrict__ W,
    float* __restrict__ out)
{
    __shared__ float lg[4][32][NE + 1];
    const int tid = threadIdx.x;
    const int w = tid >> 6, l = tid & 63;
    const int j = l & 15, g = l >> 4;
    const int bt0 = blockIdx.x * 32;
    const int kb = w * 512;
    const float* xp0 = x + (size_t)(bt0 + j) * DIMK + kb + 8 * g;
    const float* xp1 = xp0 + (size_t)16 * DIMK;
    const float* wpp = W + (size_t)j * DIMK + kb + 8 * g;
    f32x4 acc[2][4];
#pragma unroll
    for (int m = 0; m < 2; ++m)
#pragma unroll
        for (int n = 0; n < 4; ++n) acc[m][n] = (f32x4){0.f, 0.f, 0.f, 0.f};
    float4 xA[2][2], wA[4][2], xB[2][2], wB[4][2];
    load_step(xp0, xp1, wpp, 0, xA, wA);
#pragma unroll 1
    for (int s = 0; s < 16; s += 2) {
        load_step(xp0, xp1, wpp, 32 * (s + 1), xB, wB);
        do_step(xA, wA, acc);
        if (s + 2 < 16) load_step(xp0, xp1, wpp, 32 * (s + 2), xA, wA);
        do_step(xB, wB, acc);
    }
#pragma unroll
    for (int m = 0; m < 2; ++m)
#pragma unroll
        for (int n = 0; n < 4; ++n)
#pragma unroll
            for (int q = 0; q < 4; ++q)
                lg[w][16 * m + 4 * g + q][16 * n + j] = acc[m][n][q];
    __syncthreads();
#pragma unroll
    for (int r = 0; r < 8; ++r) {
        const int idx = tid + r * 256;
        const int t = idx >> 6, e = idx & 63;
        lg[0][t][e] += lg[1][t][e] + lg[2][t][e] + lg[3][t][e];
    }
    __syncthreads();
    if (tid < 32) {
        const float* rowp = &lg[0][tid][0];
        float mx = -3.402823466e38f;
        for (int e = 0; e < NE; ++e) mx = fmaxf(mx, rowp[e]);
        float sden = 0.f;
        for (int e = 0; e < NE; ++e) sden += expf(rowp[e] - mx);
        float tv[TOPKK]; int ti[TOPKK];
#pragma unroll
        for (int i = 0; i < TOPKK; ++i) { tv[i] = -3.402823466e38f; ti[i] = 0; }
        for (int e = 0; e < NE; ++e) {
            const float v = rowp[e];
            if (v > tv[TOPKK - 1]) {
                tv[TOPKK - 1] = v; ti[TOPKK - 1] = e;
#pragma unroll
                for (int q = TOPKK - 1; q > 0; --q)
                    if (tv[q] > tv[q - 1]) {
                        const float fv = tv[q]; tv[q] = tv[q - 1]; tv[q - 1] = fv;
                        const int iv = ti[q]; ti[q] = ti[q - 1]; ti[q - 1] = iv;
                    }
            }
        }
        float* ow = out + (size_t)(bt0 + tid) * TOPKK;
        float* oi = out + (size_t)NT * TOPKK + (size_t)(bt0 + tid) * TOPKK;
#pragma unroll
        for (int i = 0; i < TOPKK; ++i) {
            ow[i] = expf(tv[i] - mx) / sden;
            oi[i] = (float)ti[i];
        }
    }
}

extern "C" void kernel_launch(void* const* d_in, const int* in_sizes, int n_in,
                              void* d_out, int out_size, void* d_ws, size_t ws_size,
                              hipStream_t stream) {
    const float* x = (const float*)d_in[0];
    const float* W = (const float*)d_in[1];
    float* out = (float*)d_out;
    if (ws_size >= (size_t)WS_BYTES) {
        short* wp = (short*)d_ws;
        hipLaunchKernelGGL(pack_w_kernel, dim3(256), dim3(64), 0, stream, W, wp);
        hipLaunchKernelGGL(gate_main_kernel, dim3(NT / TT), dim3(512), 0, stream,
                           x, wp, out);
    } else {
        hipLaunchKernelGGL(gate_fallback_kernel, dim3(NT / 32), dim3(256), 0, stream,
                           x, W, out);
    }
}

// Round 4
// 64.191 us; speedup vs baseline: 1.1476x; 1.1476x over previous
//
#include <hip/hip_runtime.h>

// MoE gate: logits = x @ W^T (x:[16384,2048] f32, W:[64,2048] f32),
// softmax over 64 experts, top-8 -> weights f32 + indices stored as f32.
//
// R4: pack_w (W -> fragment-ordered bf16 3-way split triples in d_ws, 768KB,
// L2-resident) + main kernel: grid 512, 256 thr, tile 32tok x 64exp, BK=64
// double-buffered. x staged ROW-MAJOR with granule-XOR source pre-swizzle
// (keeps 128B coalescing) + matching XOR on ds_read (conflict-free). W staged
// fragment-linear (naturally conflict-free). Counted vmcnt(8) + raw s_barrier
// (no vmcnt(0) drain in loop). LDS 64KB -> 2 blocks/CU. 6-product bf16 MFMA.

typedef __attribute__((ext_vector_type(8))) short short8;
typedef __attribute__((ext_vector_type(4))) float f32x4;

#define NT    16384
#define DIMK  2048
#define NE    64
#define TOPKK 8
#define TT    32
#define CH    32
#define WS_BYTES (CH * 24 * 1024)   // 786432

union U4S8 { unsigned int u[4]; short8 s; };

// Bit-exact 3-way bf16 split of 8 f32 (truncation; subtractions exact).
__device__ __forceinline__ void split3(const float4 a, const float4 b,
                                       short8& H, short8& M, short8& L) {
    const float f[8] = {a.x, a.y, a.z, a.w, b.x, b.y, b.z, b.w};
    U4S8 uh, um, ul;
#pragma unroll
    for (int p = 0; p < 4; ++p) {
        const float f0 = f[2 * p], f1 = f[2 * p + 1];
        const unsigned int t0 = __float_as_uint(f0) & 0xFFFF0000u;
        const unsigned int t1 = __float_as_uint(f1) & 0xFFFF0000u;
        uh.u[p] = (t0 >> 16) | t1;
        const float r0 = f0 - __uint_as_float(t0);
        const float r1 = f1 - __uint_as_float(t1);
        const unsigned int v0 = __float_as_uint(r0) & 0xFFFF0000u;
        const unsigned int v1 = __float_as_uint(r1) & 0xFFFF0000u;
        um.u[p] = (v0 >> 16) | v1;
        const float s0 = r0 - __uint_as_float(v0);
        const float s1 = r1 - __uint_as_float(v1);
        ul.u[p] = (__float_as_uint(s0) >> 16) | (__float_as_uint(s1) & 0xFFFF0000u);
    }
    H = uh.s; M = um.s; L = ul.s;
}

__device__ __forceinline__ f32x4 mfma6(short8 ah, short8 am, short8 al,
                                       short8 bh, short8 bm, short8 bl, f32x4 c) {
    c = __builtin_amdgcn_mfma_f32_16x16x32_bf16(ah, bh, c, 0, 0, 0);
    c = __builtin_amdgcn_mfma_f32_16x16x32_bf16(ah, bm, c, 0, 0, 0);
    c = __builtin_amdgcn_mfma_f32_16x16x32_bf16(am, bh, c, 0, 0, 0);
    c = __builtin_amdgcn_mfma_f32_16x16x32_bf16(ah, bl, c, 0, 0, 0);
    c = __builtin_amdgcn_mfma_f32_16x16x32_bf16(am, bm, c, 0, 0, 0);
    c = __builtin_amdgcn_mfma_f32_16x16x32_bf16(al, bh, c, 0, 0, 0);
    return c;
}

__device__ __forceinline__ void async16(void* lds, const void* gp) {
    __builtin_amdgcn_global_load_lds(
        (const __attribute__((address_space(1))) unsigned int*)gp,
        (__attribute__((address_space(3))) unsigned int*)lds, 16, 0, 0);
}

#define SCHED_FENCE() __builtin_amdgcn_sched_barrier(0)
#define VM_WAIT8() do { asm volatile("s_waitcnt vmcnt(8)" ::: "memory"); SCHED_FENCE(); } while (0)
#define VM_WAIT0() do { asm volatile("s_waitcnt vmcnt(0)" ::: "memory"); SCHED_FENCE(); } while (0)
#define BAR() do { SCHED_FENCE(); __builtin_amdgcn_s_barrier(); SCHED_FENCE(); } while (0)

// ---- pack W -> fragment-ordered bf16 triples in ws ----
// [c(32)][fw=(sp*4+n)*3+t][lane(64)][8 bf16]; lane l: expert 16n+(l&15),
// k = 64c + 32sp + 8(l>>4) + 0..7.
__global__ __launch_bounds__(64) void pack_w_kernel(
    const float* __restrict__ W, short* __restrict__ wp)
{
    const int b = blockIdx.x;            // ((c*2)+sp)*4 + n
    const int c = b >> 3, sp = (b >> 2) & 1, n = b & 3;
    const int l = threadIdx.x;
    const float* g = W + (size_t)(16 * n + (l & 15)) * DIMK
                       + 64 * c + 32 * sp + 8 * (l >> 4);
    const float4 lo = *(const float4*)g;
    const float4 hi = *(const float4*)(g + 4);
    short8 H, M, L;
    split3(lo, hi, H, M, L);
    const size_t base = ((size_t)c * 24 + (sp * 4 + n) * 3) * 512 + l * 8;
    *(short8*)(wp + base)        = H;
    *(short8*)(wp + base + 512)  = M;
    *(short8*)(wp + base + 1024) = L;
}

// ---- main fused kernel ----
__global__ __launch_bounds__(256, 2) void gate_main_kernel(
    const float* __restrict__ x, const short* __restrict__ wp,
    float* __restrict__ out)
{
    // smem map: [0,16384) = xs 2 bufs x 8KB (32 rows x 256B, granule-XOR-swz)
    //           [16384,65536) = wl 2 bufs x 24KB (24 frags x 1KB, linear)
    //           lg (32 x 65 f32 = 8.3KB) aliases xs after the K-loop.
    __shared__ __align__(16) char smem[65536];

    const int tid = threadIdx.x;
    const int w   = tid >> 6;       // 4 waves
    const int l   = tid & 63;
    const int lj  = l & 15;
    const int lq  = l >> 4;
    const int tg  = w >> 1;         // token group (16 tokens)
    const int eg  = w & 1;          // expert group (32 experts)
    const int bt0 = blockIdx.x * TT;

    // stage: wave w -> x instrs {2w,2w+1} (4 rows x 256B each, contiguous
    // source with XOR'd 16B granules), W instrs {6w..6w+5} (1KB contiguous).
#define STAGE(cc, B) do {                                                     \
    _Pragma("unroll")                                                         \
    for (int ii = 0; ii < 2; ++ii) {                                          \
        const int i = 2 * w + ii;                                             \
        const int r = 4 * i + lq;                                             \
        const float* gsrc = x + (size_t)(bt0 + r) * DIMK + (cc) * 64          \
                              + ((lj ^ (r & 7)) << 2);                        \
        async16(smem + (B) * 8192 + i * 1024, gsrc);                          \
    }                                                                         \
    _Pragma("unroll")                                                         \
    for (int ii = 0; ii < 6; ++ii) {                                          \
        const int f = 6 * w + ii;                                             \
        const short* gs = wp + ((size_t)(cc) * 24 + f) * 512 + l * 8;         \
        async16(smem + 16384 + (B) * 24576 + f * 1024, gs);                   \
    }                                                                         \
} while (0)

#define COMPUTE(B) do {                                                       \
    const float4* xv = (const float4*)(smem + (B) * 8192);                    \
    const short8* wv = (const short8*)(smem + 16384 + (B) * 24576);           \
    _Pragma("unroll")                                                         \
    for (int sp = 0; sp < 2; ++sp) {                                          \
        const int row = 16 * tg + lj;                                         \
        const int rx  = row & 7;                                              \
        const float4 a0 = xv[row * 16 + ((8 * sp + 2 * lq + 0) ^ rx)];        \
        const float4 a1 = xv[row * 16 + ((8 * sp + 2 * lq + 1) ^ rx)];        \
        short8 ah, am, al_;                                                   \
        split3(a0, a1, ah, am, al_);                                          \
        _Pragma("unroll")                                                     \
        for (int nt = 0; nt < 2; ++nt) {                                      \
            const int n  = 2 * eg + nt;                                       \
            const int fb = (sp * 4 + n) * 3;                                  \
            const short8 bh = wv[(fb + 0) * 64 + l];                          \
            const short8 bm = wv[(fb + 1) * 64 + l];                          \
            const short8 bl = wv[(fb + 2) * 64 + l];                          \
            acc[nt] = mfma6(ah, am, al_, bh, bm, bl, acc[nt]);                \
        }                                                                     \
    }                                                                         \
} while (0)

    f32x4 acc[2];
#pragma unroll
    for (int nt = 0; nt < 2; ++nt) acc[nt] = (f32x4){0.f, 0.f, 0.f, 0.f};

    STAGE(0, 0);
    STAGE(1, 1);

#pragma unroll 1
    for (int c = 0; c < CH; c += 2) {
        VM_WAIT8();                 // stage(c) landed; stage(c+1) in flight
        BAR();
        COMPUTE(0);                 // chunk c
        BAR();                      // all reads of buf0 done
        if (c + 2 < CH) { STAGE(c + 2, 0); VM_WAIT8(); }  // drains stage(c+1)
        else            { VM_WAIT0(); }
        BAR();
        COMPUTE(1);                 // chunk c+1
        BAR();                      // all reads of buf1 done
        if (c + 3 < CH) STAGE(c + 3, 1);
    }

    // ---- logits -> lg (aliases xs; safe after final BAR) ----
    // C/D: token = 16tg + 4*(l>>4) + q, expert = 32eg + 16nt + (l&15)
    float* lg = (float*)smem;
#pragma unroll
    for (int nt = 0; nt < 2; ++nt)
#pragma unroll
        for (int q = 0; q < 4; ++q)
            lg[(16 * tg + 4 * lq + q) * (NE + 1) + 32 * eg + 16 * nt + lj] =
                acc[nt][q];
    __syncthreads();

    // ---- fused softmax + top-8: one lane per token ----
    if (tid < TT) {
        const float* rowp = lg + tid * (NE + 1);
        float mx = -3.402823466e38f;
        for (int e = 0; e < NE; ++e) mx = fmaxf(mx, rowp[e]);
        float sden = 0.f;
        for (int e = 0; e < NE; ++e) sden += expf(rowp[e] - mx);

        float tv[TOPKK];
        int   ti[TOPKK];
#pragma unroll
        for (int i = 0; i < TOPKK; ++i) { tv[i] = -3.402823466e38f; ti[i] = 0; }
        for (int e = 0; e < NE; ++e) {
            const float v = rowp[e];
            if (v > tv[TOPKK - 1]) {
                tv[TOPKK - 1] = v; ti[TOPKK - 1] = e;
#pragma unroll
                for (int q = TOPKK - 1; q > 0; --q) {
                    if (tv[q] > tv[q - 1]) {
                        const float fv = tv[q]; tv[q] = tv[q - 1]; tv[q - 1] = fv;
                        const int   iv = ti[q]; ti[q] = ti[q - 1]; ti[q - 1] = iv;
                    }
                }
            }
        }
        float* ow = out + (size_t)(bt0 + tid) * TOPKK;
        float* oi = out + (size_t)NT * TOPKK + (size_t)(bt0 + tid) * TOPKK;
#pragma unroll
        for (int i = 0; i < TOPKK; ++i) {
            ow[i] = expf(tv[i] - mx) / sden;   // ROUTE_SCALE == 1.0
            oi[i] = (float)ti[i];
        }
    }
#undef STAGE
#undef COMPUTE
}

// ================= fallback (R2 kernel) if ws too small =================
__device__ __forceinline__ void load_step(const float* xp0, const float* xp1,
                                          const float* wp, int koff,
                                          float4 xb[2][2], float4 wb[4][2]) {
#pragma unroll
    for (int h = 0; h < 2; ++h) {
        xb[0][h] = *(const float4*)(xp0 + koff + 4 * h);
        xb[1][h] = *(const float4*)(xp1 + koff + 4 * h);
    }
#pragma unroll
    for (int n = 0; n < 4; ++n)
#pragma unroll
        for (int h = 0; h < 2; ++h)
            wb[n][h] = *(const float4*)(wp + (size_t)n * 16 * DIMK + koff + 4 * h);
}

__device__ __forceinline__ void do_step(const float4 xc[2][2], const float4 wc[4][2],
                                        f32x4 acc[2][4]) {
    short8 ah[2], am[2], al[2];
#pragma unroll
    for (int m = 0; m < 2; ++m) split3(xc[m][0], xc[m][1], ah[m], am[m], al[m]);
#pragma unroll
    for (int n = 0; n < 4; ++n) {
        short8 bh, bm, bl;
        split3(wc[n][0], wc[n][1], bh, bm, bl);
#pragma unroll
        for (int m = 0; m < 2; ++m)
            acc[m][n] = mfma6(ah[m], am[m], al[m], bh, bm, bl, acc[m][n]);
    }
}

__global__ __launch_bounds__(256, 2) void gate_fallback_kernel(
    const float* __restrict__ x, const float* __restrict__ W,
    float* __restrict__ out)
{
    __shared__ float lg[4][32][NE + 1];
    const int tid = threadIdx.x;
    const int w = tid >> 6, l = tid & 63;
    const int j = l & 15, g = l >> 4;
    const int bt0 = blockIdx.x * 32;
    const int kb = w * 512;
    const float* xp0 = x + (size_t)(bt0 + j) * DIMK + kb + 8 * g;
    const float* xp1 = xp0 + (size_t)16 * DIMK;
    const float* wpp = W + (size_t)j * DIMK + kb + 8 * g;
    f32x4 acc[2][4];
#pragma unroll
    for (int m = 0; m < 2; ++m)
#pragma unroll
        for (int n = 0; n < 4; ++n) acc[m][n] = (f32x4){0.f, 0.f, 0.f, 0.f};
    float4 xA[2][2], wA[4][2], xB[2][2], wB[4][2];
    load_step(xp0, xp1, wpp, 0, xA, wA);
#pragma unroll 1
    for (int s = 0; s < 16; s += 2) {
        load_step(xp0, xp1, wpp, 32 * (s + 1), xB, wB);
        do_step(xA, wA, acc);
        if (s + 2 < 16) load_step(xp0, xp1, wpp, 32 * (s + 2), xA, wA);
        do_step(xB, wB, acc);
    }
#pragma unroll
    for (int m = 0; m < 2; ++m)
#pragma unroll
        for (int n = 0; n < 4; ++n)
#pragma unroll
            for (int q = 0; q < 4; ++q)
                lg[w][16 * m + 4 * g + q][16 * n + j] = acc[m][n][q];
    __syncthreads();
#pragma unroll
    for (int r = 0; r < 8; ++r) {
        const int idx = tid + r * 256;
        const int t = idx >> 6, e = idx & 63;
        lg[0][t][e] += lg[1][t][e] + lg[2][t][e] + lg[3][t][e];
    }
    __syncthreads();
    if (tid < 32) {
        const float* rowp = &lg[0][tid][0];
        float mx = -3.402823466e38f;
        for (int e = 0; e < NE; ++e) mx = fmaxf(mx, rowp[e]);
        float sden = 0.f;
        for (int e = 0; e < NE; ++e) sden += expf(rowp[e] - mx);
        float tv[TOPKK]; int ti[TOPKK];
#pragma unroll
        for (int i = 0; i < TOPKK; ++i) { tv[i] = -3.402823466e38f; ti[i] = 0; }
        for (int e = 0; e < NE; ++e) {
            const float v = rowp[e];
            if (v > tv[TOPKK - 1]) {
                tv[TOPKK - 1] = v; ti[TOPKK - 1] = e;
#pragma unroll
                for (int q = TOPKK - 1; q > 0; --q)
                    if (tv[q] > tv[q - 1]) {
                        const float fv = tv[q]; tv[q] = tv[q - 1]; tv[q - 1] = fv;
                        const int iv = ti[q]; ti[q] = ti[q - 1]; ti[q - 1] = iv;
                    }
            }
        }
        float* ow = out + (size_t)(bt0 + tid) * TOPKK;
        float* oi = out + (size_t)NT * TOPKK + (size_t)(bt0 + tid) * TOPKK;
#pragma unroll
        for (int i = 0; i < TOPKK; ++i) {
            ow[i] = expf(tv[i] - mx) / sden;
            oi[i] = (float)ti[i];
        }
    }
}

extern "C" void kernel_launch(void* const* d_in, const int* in_sizes, int n_in,
                              void* d_out, int out_size, void* d_ws, size_t ws_size,
                              hipStream_t stream) {
    const float* x = (const float*)d_in[0];
    const float* W = (const float*)d_in[1];
    float* out = (float*)d_out;
    if (ws_size >= (size_t)WS_BYTES) {
        short* wp = (short*)d_ws;
        hipLaunchKernelGGL(pack_w_kernel, dim3(256), dim3(64), 0, stream, W, wp);
        hipLaunchKernelGGL(gate_main_kernel, dim3(NT / TT), dim3(256), 0, stream,
                           x, wp, out);
    } else {
        hipLaunchKernelGGL(gate_fallback_kernel, dim3(NT / 32), dim3(256), 0, stream,
                           x, W, out);
    }
}